// Round 2
// baseline (18049.861 us; speedup 1.0000x reference)
//
#include <hip/hip_runtime.h>

#define S_  2048
#define B_  8
#define H_  512
#define H2_ 1024
#define CM_ 4096   // pass-1 chunk rows (proj rows per chunk)

__device__ __forceinline__ float gelu_f(float x){
    return 0.5f * x * (1.0f + erff(x * 0.7071067811865476f));
}

// Tiled fp32 GEMM: C = epilogue(A @ Bm + bias). BM=BN=64, BK=16, 256 thr, 4x4/thr.
// INMAP 0: A row r at A + r*K (A pre-offset by caller for chunking)
// INMAP 1: hidden transpose, global row gr=r0+r: s=gr>>3,b=gr&7 -> hidden+((b*S_+s)*H_)
// INMAP 2: gather beams (K=2): gr=r: s=gr>>4, j=(gr>>3)&1, b=gr&7, idx=sel[s*2+j],
//          kb=idx>>2 -> A + ((s*2+kb)*8+b)*H_
// INMAP 3: gather hidden (depth 0): same decode, kb==0 -> hidden+((b*S_+s)*H_)
template<bool GELU, int INMAP>
__global__ __launch_bounds__(256)
void gemm_k(const float* __restrict__ A, const float* __restrict__ Bm,
            const float* __restrict__ bias, float* __restrict__ C,
            int N, int K, int r0, const int* __restrict__ sel)
{
    __shared__ float As[16][64];
    __shared__ float Bs[16][64];
    const int t  = threadIdx.x;
    const int m0 = blockIdx.x * 64;
    const int n0 = blockIdx.y * 64;

    const int lr   = t >> 2;
    const int lc   = (t & 3) * 4;
    const int brow = t >> 4;
    const int bcol = (t & 15) * 4;

    size_t aoff;
    {
        int r = m0 + lr;
        if (INMAP == 1) {
            int gr = r0 + r; int s = gr >> 3, b = gr & 7;
            aoff = ((size_t)b * S_ + s) * H_;
        } else if (INMAP == 2) {
            int s = r >> 4, j = (r >> 3) & 1, b = r & 7;
            int idx = sel[s * 2 + j]; int kb = idx >> 2;
            aoff = ((size_t)(s * 2 + kb) * 8 + b) * H_;
        } else if (INMAP == 3) {
            int s = r >> 4, b = r & 7;
            aoff = ((size_t)b * S_ + s) * H_;
        } else {
            aoff = (size_t)r * K;
        }
    }

    float acc[4][4];
    #pragma unroll
    for (int i = 0; i < 4; i++)
        #pragma unroll
        for (int j = 0; j < 4; j++) acc[i][j] = 0.f;

    const int ty = t >> 4, tx = t & 15;

    for (int k0 = 0; k0 < K; k0 += 16) {
        float4 a4 = *(const float4*)(A + aoff + k0 + lc);
        float4 b4 = *(const float4*)(Bm + (size_t)(k0 + brow) * N + n0 + bcol);
        As[lc + 0][lr] = a4.x;
        As[lc + 1][lr] = a4.y;
        As[lc + 2][lr] = a4.z;
        As[lc + 3][lr] = a4.w;
        *(float4*)&Bs[brow][bcol] = b4;
        __syncthreads();
        #pragma unroll
        for (int k = 0; k < 16; k++) {
            float4 av = ((const float4*)&As[k][0])[ty];
            float4 bv = ((const float4*)&Bs[k][0])[tx];
            float ai[4] = {av.x, av.y, av.z, av.w};
            float bj[4] = {bv.x, bv.y, bv.z, bv.w};
            #pragma unroll
            for (int i = 0; i < 4; i++)
                #pragma unroll
                for (int j = 0; j < 4; j++) acc[i][j] += ai[i] * bj[j];
        }
        __syncthreads();
    }

    #pragma unroll
    for (int i = 0; i < 4; i++) {
        int r = m0 + ty * 4 + i;
        size_t coff = (size_t)r * N;
        float4 v;
        float* vp = &v.x;
        #pragma unroll
        for (int j = 0; j < 4; j++) {
            float c = acc[i][j] + bias[n0 + tx * 4 + j];
            if (GELU) c = gelu_f(c);
            vp[j] = c;
        }
        *(float4*)(C + coff + n0 + tx * 4) = v;
    }
}

// One wave per row of h2 (CM_ rows): ev[((pr>>3)*4+n)*8 + (pr&7)] = sigmoid(dot+be3)
__global__ __launch_bounds__(256)
void score1_k(const float* __restrict__ h2, const float* __restrict__ We3,
              const float* __restrict__ be3, float* __restrict__ ev,
              int pr0, int n)
{
    int row  = blockIdx.x * 4 + (threadIdx.x >> 6);
    int lane = threadIdx.x & 63;
    const float* p = h2 + (size_t)row * H_;
    float s = 0.f;
    #pragma unroll
    for (int j = 0; j < H_ / 64; j++) s += p[lane + 64 * j] * We3[lane + 64 * j];
    #pragma unroll
    for (int off = 32; off > 0; off >>= 1) s += __shfl_down(s, off, 64);
    if (lane == 0) {
        int pr = pr0 + row;
        ev[(size_t)(pr >> 3) * 32 + n * 8 + (pr & 7)] = 1.0f / (1.0f + expf(-(s + be3[0])));
    }
}

// sc[i] = mean over 8 consecutive ev rows / TEMPERATURE
__global__ __launch_bounds__(256)
void score2_k(const float* __restrict__ ev, float* __restrict__ sc, int n)
{
    int i = blockIdx.x * 256 + threadIdx.x;
    if (i >= n) return;
    float s = 0.f;
    #pragma unroll
    for (int b = 0; b < 8; b++) s += ev[i * 8 + b];
    sc[i] = (s * 0.125f) / 0.8f;
}

// Exact replication of reference keep-mask + stable top-2 + valid fallback.
__global__ __launch_bounds__(256)
void select_k(const float* __restrict__ sc, int* __restrict__ sel, int K)
{
    int s = blockIdx.x * 256 + threadIdx.x;
    if (s >= S_) return;
    int K4 = K * 4;
    float cand[8];
    for (int k = 0; k < K; k++) {
        const float* scp = sc + (size_t)(s * K + k) * 4;
        bool keep[4] = {false, false, false, false};
        int count = 0;
        for (int i = 0; i < 4; i++) {
            float mind = INFINITY;
            for (int j = 0; j < 4; j++)
                if (keep[j]) mind = fminf(mind, fabsf(scp[i] - scp[j]));
            bool ki = ((count == 0) || (mind >= 0.1f)) && (count < 2);
            keep[i] = ki;
            if (ki) count++;
        }
        for (int i = 0; i < 4; i++) cand[k * 4 + i] = keep[i] ? scp[i] : -INFINITY;
    }
    int i0 = 0;
    for (int i = 1; i < K4; i++) if (cand[i] > cand[i0]) i0 = i;
    int i1 = -1;
    for (int i = 0; i < K4; i++) {
        if (i == i0) continue;
        if (i1 < 0 || cand[i] > cand[i1]) i1 = i;
    }
    if (!(cand[i1] > -INFINITY)) i1 = i0;
    sel[s * 2 + 0] = i0;
    sel[s * 2 + 1] = i1;
}

// Pass-2 second matmul: one block per (s,j). beams[(s*2+j)*8+r] = gelu(projg_rows @ Wb[n] + bb[n])
__global__ __launch_bounds__(256)
void branch2_k(const float* __restrict__ projg, const float* __restrict__ Wb,
               const float* __restrict__ bb, const int* __restrict__ sel,
               float* __restrict__ beams)
{
    __shared__ float Asm[8][H_];
    const int t = threadIdx.x;
    const int base = blockIdx.x * 8;            // projg/beams row base
    const int s = blockIdx.x >> 1, j = blockIdx.x & 1;
    const int idx = sel[s * 2 + j];
    const int n = idx & 3;

    const float4* src = (const float4*)(projg + (size_t)base * H_);
    #pragma unroll
    for (int q = 0; q < 4; q++) {
        int i4 = t + q * 256;                   // 1024 float4 total
        ((float4*)&Asm[0][0])[i4] = src[i4];
    }
    __syncthreads();

    const float* Wn  = Wb + (size_t)n * H_ * H_;
    const float* bbn = bb + n * H_;
    const int r = t >> 5, g = t & 31;

    #pragma unroll
    for (int cc = 0; cc < 4; cc++) {
        int c = cc * 128 + g * 4;
        float a0 = 0.f, a1 = 0.f, a2 = 0.f, a3 = 0.f;
        #pragma unroll 4
        for (int k = 0; k < H_; k++) {
            float a = Asm[r][k];
            float4 w = *(const float4*)(Wn + (size_t)k * H_ + c);
            a0 += a * w.x; a1 += a * w.y; a2 += a * w.z; a3 += a * w.w;
        }
        float4 o;
        o.x = gelu_f(a0 + bbn[c + 0]);
        o.y = gelu_f(a1 + bbn[c + 1]);
        o.z = gelu_f(a2 + bbn[c + 2]);
        o.w = gelu_f(a3 + bbn[c + 3]);
        *(float4*)(beams + ((size_t)base + r) * H_ + c) = o;
    }
}

// out[b][s][:] = beams[(s*2+0)*8+b][:] + hidden[b][s][:]
__global__ __launch_bounds__(256)
void final_add_k(const float* __restrict__ beams, const float* __restrict__ hidden,
                 float* __restrict__ out)
{
    size_t tid = (size_t)blockIdx.x * 256 + threadIdx.x;
    const size_t total = (size_t)B_ * S_ * (H_ / 4);
    if (tid >= total) return;
    int h4 = tid & (H_ / 4 - 1);
    int s  = (tid >> 7) & (S_ - 1);
    int b  = tid >> 18;
    float4 v  = ((const float4*)(beams + ((size_t)(s * 2 + 0) * 8 + b) * H_))[h4];
    float4 hd = ((const float4*)(hidden + ((size_t)b * S_ + s) * H_))[h4];
    v.x += hd.x; v.y += hd.y; v.z += hd.z; v.w += hd.w;
    ((float4*)(out + ((size_t)b * S_ + s) * H_))[h4] = v;
}

extern "C" void kernel_launch(void* const* d_in, const int* in_sizes, int n_in,
                              void* d_out, int out_size, void* d_ws, size_t ws_size,
                              hipStream_t stream)
{
    const float* hidden = (const float*)d_in[0];
    const float* We1 = (const float*)d_in[1];
    const float* be1 = (const float*)d_in[2];
    const float* We2 = (const float*)d_in[3];
    const float* be2 = (const float*)d_in[4];
    const float* We3 = (const float*)d_in[5];
    const float* be3 = (const float*)d_in[6];
    const float* Wp  = (const float*)d_in[7];
    const float* bp  = (const float*)d_in[8];
    const float* Wb  = (const float*)d_in[9];
    const float* bb  = (const float*)d_in[10];
    (void)in_sizes; (void)n_in; (void)ws_size;

    // d_ws: R0 beams (16,777,216 f) | R1 scratch (16,777,216 f)  = 128 MB total
    float* beams = (float*)d_ws;
    float* R1    = beams + 16777216;
    float* projc = R1;                    //  2,097,152 (CM_*512)
    float* thc   = R1 + 2097152;          //  2,097,152
    float* h1    = R1 + 4194304;          //  4,194,304 (CM_*1024)
    float* h2    = R1 + 8388608;          //  2,097,152
    float* projg = R1;                    // 16,777,216 (pass 2, reuses whole R1)

    // small buffers live in the tail of d_out (dead before final_add writes)
    float* outf = (float*)d_out;
    float* evb  = outf + (out_size - 262144);   // 131,072 floats
    float* scb  = evb + 131072;                 //  16,384 floats
    int*   sel  = (int*)(scb + 16384);          //   4,096 ints

    for (int d = 0; d < 3; d++) {
        const int K  = (d == 0) ? 1 : 2;
        const int Mp = S_ * K * B_;             // proj rows this depth
        const int NC = Mp / CM_;

        // ---- pass 1: scores (chunked, states discarded) ----
        for (int c = 0; c < NC; c++) {
            dim3 gp(CM_ / 64, H_ / 64);
            if (d == 0)
                gemm_k<false, 1><<<gp, 256, 0, stream>>>(hidden, Wp, bp, projc,
                                                         H_, H_, c * CM_, nullptr);
            else
                gemm_k<false, 0><<<gp, 256, 0, stream>>>(beams + (size_t)c * CM_ * H_,
                                                         Wp, bp, projc, H_, H_, 0, nullptr);
            for (int n = 0; n < 4; n++) {
                gemm_k<true, 0><<<gp, 256, 0, stream>>>(projc, Wb + (size_t)n * H_ * H_,
                                                        bb + n * H_, thc, H_, H_, 0, nullptr);
                dim3 g1(CM_ / 64, H2_ / 64);
                gemm_k<true, 0><<<g1, 256, 0, stream>>>(thc, We1, be1, h1, H2_, H_, 0, nullptr);
                dim3 g2(CM_ / 64, H_ / 64);
                gemm_k<true, 0><<<g2, 256, 0, stream>>>(h1, We2, be2, h2, H_, H2_, 0, nullptr);
                score1_k<<<CM_ / 4, 256, 0, stream>>>(h2, We3, be3, evb, c * CM_, n);
            }
        }

        // ---- selection ----
        const int nsc = S_ * K * 4;
        score2_k<<<(nsc + 255) / 256, 256, 0, stream>>>(evb, scb, nsc);
        select_k<<<(S_ + 255) / 256, 256, 0, stream>>>(scb, sel, K);

        // ---- pass 2: recompute selected states only ----
        dim3 gg(32768 / 64, H_ / 64);   // 32768 = S*2*8 gathered rows
        if (d == 0)
            gemm_k<false, 3><<<gg, 256, 0, stream>>>(hidden, Wp, bp, projg,
                                                     H_, H_, 0, sel);
        else
            gemm_k<false, 2><<<gg, 256, 0, stream>>>(beams, Wp, bp, projg,
                                                     H_, H_, 0, sel);
        branch2_k<<<S_ * 2, 256, 0, stream>>>(projg, Wb, bb, sel, beams);
    }

    final_add_k<<<(int)(((size_t)B_ * S_ * (H_ / 4) + 255) / 256), 256, 0, stream>>>(
        beams, hidden, outf);
}

// Round 4
// 6910.122 us; speedup vs baseline: 2.6121x; 2.6121x over previous
//
#include <hip/hip_runtime.h>

#define S_  2048
#define B_  8
#define H_  512
#define H2_ 1024
#define CM_ 8192   // pass-1 chunk rows

typedef _Float16 f16x8 __attribute__((ext_vector_type(8)));
typedef _Float16 f16x4 __attribute__((ext_vector_type(4)));
typedef float    f32x4 __attribute__((ext_vector_type(4)));

__device__ __forceinline__ float gelu_f(float x){
    return 0.5f * x * (1.0f + erff(x * 0.7071067811865476f));
}

// ---------------------------------------------------------------------------
// Weight prep: decompose fp32 K×N (row-major) into 2 fp16 planes in
// MFMA-fragment order: plane[( (fc*KS + ks)*64 + l )*8 + j] holds
// B[ks*32 + (l>>4)*8 + j][fc*16 + (l&15)].  plane2 = (residual * 2048).
__global__ __launch_bounds__(256)
void prep_k(const float* __restrict__ src, _Float16* __restrict__ dst,
            int K, int N)
{
    int g = blockIdx.x * 256 + threadIdx.x;        // total = K*N/8
    int KS = K >> 5;
    int l  = g & 63;
    int rem = g >> 6;
    int ks = rem % KS;
    int fc = rem / KS;
    int kbase = ks * 32 + (l >> 4) * 8;
    int col   = fc * 16 + (l & 15);
    size_t KN = (size_t)K * N;
    #pragma unroll
    for (int j = 0; j < 8; j++) {
        float x = src[(size_t)(kbase + j) * N + col];
        _Float16 h1 = (_Float16)x;
        float r = x - (float)h1;
        _Float16 h2 = (_Float16)(r * 2048.0f);
        dst[(size_t)g * 8 + j]      = h1;
        dst[KN + (size_t)g * 8 + j] = h2;
    }
}

// ---------------------------------------------------------------------------
// Split-precision fp16x2 MFMA GEMM.  C = epi(A(f32) @ B + bias).
// BM=64, BN=128, BK=32, 256 threads (4 waves, 2x2, wave tile 32x64).
// B read directly from prepped global planes (no LDS). A staged f32->f16x2
// into frag-order LDS with XOR swizzle.
// INMAP 0: A row r at A + r*K
// INMAP 1: hidden transpose: gr=r0+r: hidden + ((gr&7)*S_ + (gr>>3))*H_
// INMAP 2: gather beams: s=r>>4, j=(r>>3)&1, b=r&7, kb=sel[s*2+j]>>2
//          -> A + ((s*2+kb)*8+b)*H_
// INMAP 3: gather hidden: s=r>>4, b=r&7 -> hidden + (b*S_+s)*H_
template<bool GELU, int INMAP>
__global__ __launch_bounds__(256, 2)
void mgemm_k(const float* __restrict__ A, const _Float16* __restrict__ Bp,
             const float* __restrict__ bias, float* __restrict__ C,
             int N, int K, int r0, const int* __restrict__ sel)
{
    __shared__ __align__(16) char smem[8192];      // 2 planes * 4 fr * 64 * 16B
    const int t    = threadIdx.x;
    const int m0   = blockIdx.x * 64;
    const int n0   = blockIdx.y * 128;
    const int lane = t & 63;
    const int wave = t >> 6;
    const int wr   = wave >> 1;                    // 0..1 row half
    const int wc   = wave & 1;                     // 0..1 col half
    const int KS   = K >> 5;
    const size_t planeStride = (size_t)K * N;      // halves

    // ---- A staging assignment: q=0..1, row=(t>>3)+32q, k0=(t&7)*4 ----
    const int srow = t >> 3;
    const int sk0  = (t & 7) * 4;
    const float* aptr[2];
    int wbyte[2];
    #pragma unroll
    for (int q = 0; q < 2; q++) {
        int row = srow + 32 * q;
        int r = m0 + row;
        size_t aoff;
        if (INMAP == 1) { int gr = r0 + r; aoff = ((size_t)(gr & 7) * S_ + (gr >> 3)) * H_; }
        else if (INMAP == 2) {
            int s = r >> 4, j = (r >> 3) & 1, b = r & 7;
            int kb = sel[s * 2 + j] >> 2;
            aoff = ((size_t)(s * 2 + kb) * 8 + b) * H_;
        }
        else if (INMAP == 3) { int s = r >> 4, b = r & 7; aoff = ((size_t)b * S_ + s) * H_; }
        else aoff = (size_t)r * K;
        aptr[q] = A + aoff + sk0;
        int e = (row & 15) + 16 * (sk0 >> 3);
        int p = e ^ (((e >> 4) & 3) << 2);
        wbyte[q] = (row >> 4) * 1024 + p * 16 + (sk0 & 4) * 2;
    }

    // ---- frag read offsets ----
    const int rl    = lane ^ (((lane >> 4) & 3) << 2);
    const int rbyte = rl * 16;

    // ---- B frag pointers (global, prepped layout) ----
    const _Float16* bjp[4];
    #pragma unroll
    for (int j = 0; j < 4; j++) {
        int fcg = (n0 >> 4) + wc * 4 + j;
        bjp[j] = Bp + (size_t)fcg * KS * 512 + lane * 8;
    }

    f32x4 accM[2][4], accX[2][4];
    #pragma unroll
    for (int i = 0; i < 2; i++)
        #pragma unroll
        for (int j = 0; j < 4; j++) { accM[i][j] = (f32x4)0.0f; accX[i][j] = (f32x4)0.0f; }

    for (int ks = 0; ks < KS; ks++) {
        // global loads for this step (A f32, B frags) — issue early
        float4 av[2];
        #pragma unroll
        for (int q = 0; q < 2; q++) av[q] = *(const float4*)(aptr[q] + ks * 32);
        f16x8 b1v[4], b2v[4];
        #pragma unroll
        for (int j = 0; j < 4; j++) {
            const _Float16* bp = bjp[j] + (size_t)ks * 512;
            b1v[j] = *(const f16x8*)(bp);
            b2v[j] = *(const f16x8*)(bp + planeStride);
        }

        __syncthreads();   // previous iteration's frag reads done
        #pragma unroll
        for (int q = 0; q < 2; q++) {
            const float xs[4] = {av[q].x, av[q].y, av[q].z, av[q].w};
            f16x4 hv1, hv2;
            #pragma unroll
            for (int e = 0; e < 4; e++) {
                float x = xs[e];
                _Float16 h1 = (_Float16)x;
                hv1[e] = h1;
                hv2[e] = (_Float16)((x - (float)h1) * 2048.0f);
            }
            *(f16x4*)(smem + wbyte[q])        = hv1;
            *(f16x4*)(smem + 4096 + wbyte[q]) = hv2;
        }
        __syncthreads();

        f16x8 a1[2], a2[2];
        #pragma unroll
        for (int i = 0; i < 2; i++) {
            int off = (wr * 2 + i) * 1024 + rbyte;
            a1[i] = *(const f16x8*)(smem + off);
            a2[i] = *(const f16x8*)(smem + 4096 + off);
        }
        #pragma unroll
        for (int i = 0; i < 2; i++)
            #pragma unroll
            for (int j = 0; j < 4; j++)
                accM[i][j] = __builtin_amdgcn_mfma_f32_16x16x32_f16(a1[i], b1v[j], accM[i][j], 0, 0, 0);
        #pragma unroll
        for (int i = 0; i < 2; i++)
            #pragma unroll
            for (int j = 0; j < 4; j++)
                accX[i][j] = __builtin_amdgcn_mfma_f32_16x16x32_f16(a1[i], b2v[j], accX[i][j], 0, 0, 0);
        #pragma unroll
        for (int i = 0; i < 2; i++)
            #pragma unroll
            for (int j = 0; j < 4; j++)
                accX[i][j] = __builtin_amdgcn_mfma_f32_16x16x32_f16(a2[i], b1v[j], accX[i][j], 0, 0, 0);
    }

    // ---- epilogue ----
    const float inv2048 = 4.8828125e-4f;
    #pragma unroll
    for (int j = 0; j < 4; j++) {
        int col = n0 + wc * 64 + j * 16 + (lane & 15);
        float bv = bias[col];
        #pragma unroll
        for (int i = 0; i < 2; i++) {
            int rbase = m0 + wr * 32 + i * 16 + ((lane >> 4) << 2);
            #pragma unroll
            for (int r = 0; r < 4; r++) {
                float c = accM[i][j][r] + accX[i][j][r] * inv2048 + bv;
                if (GELU) c = gelu_f(c);
                C[(size_t)(rbase + r) * N + col] = c;
            }
        }
    }
}

// ---------------------------------------------------------------------------
// One wave per row of h2: ev[(pr>>3)*32 + n*8 + (pr&7)] = sigmoid(dot + be3)
__global__ __launch_bounds__(256)
void score1_k(const float* __restrict__ h2, const float* __restrict__ We3,
              const float* __restrict__ be3, float* __restrict__ ev,
              int pr0, int n)
{
    int row  = blockIdx.x * 4 + (threadIdx.x >> 6);
    int lane = threadIdx.x & 63;
    const float* p = h2 + (size_t)row * H_;
    float s = 0.f;
    #pragma unroll
    for (int j = 0; j < H_ / 64; j++) s += p[lane + 64 * j] * We3[lane + 64 * j];
    #pragma unroll
    for (int off = 32; off > 0; off >>= 1) s += __shfl_down(s, off, 64);
    if (lane == 0) {
        int pr = pr0 + row;
        ev[(size_t)(pr >> 3) * 32 + n * 8 + (pr & 7)] = 1.0f / (1.0f + expf(-(s + be3[0])));
    }
}

__global__ __launch_bounds__(256)
void score2_k(const float* __restrict__ ev, float* __restrict__ sc, int n)
{
    int i = blockIdx.x * 256 + threadIdx.x;
    if (i >= n) return;
    float s = 0.f;
    #pragma unroll
    for (int b = 0; b < 8; b++) s += ev[i * 8 + b];
    sc[i] = (s * 0.125f) / 0.8f;
}

__global__ __launch_bounds__(256)
void select_k(const float* __restrict__ sc, int* __restrict__ sel, int K)
{
    int s = blockIdx.x * 256 + threadIdx.x;
    if (s >= S_) return;
    int K4 = K * 4;
    float cand[8];
    for (int k = 0; k < K; k++) {
        const float* scp = sc + (size_t)(s * K + k) * 4;
        bool keep[4] = {false, false, false, false};
        int count = 0;
        for (int i = 0; i < 4; i++) {
            float mind = INFINITY;
            for (int j = 0; j < 4; j++)
                if (keep[j]) mind = fminf(mind, fabsf(scp[i] - scp[j]));
            bool ki = ((count == 0) || (mind >= 0.1f)) && (count < 2);
            keep[i] = ki;
            if (ki) count++;
        }
        for (int i = 0; i < 4; i++) cand[k * 4 + i] = keep[i] ? scp[i] : -INFINITY;
    }
    int i0 = 0;
    for (int i = 1; i < K4; i++) if (cand[i] > cand[i0]) i0 = i;
    int i1 = -1;
    for (int i = 0; i < K4; i++) {
        if (i == i0) continue;
        if (i1 < 0 || cand[i] > cand[i1]) i1 = i;
    }
    if (!(cand[i1] > -INFINITY)) i1 = i0;
    sel[s * 2 + 0] = i0;
    sel[s * 2 + 1] = i1;
}

// Pass-2 second matmul (fp32): beams[(s*2+j)*8+r] = gelu(projg @ Wb[n] + bb[n])
__global__ __launch_bounds__(256)
void branch2_k(const float* __restrict__ projg, const float* __restrict__ Wb,
               const float* __restrict__ bb, const int* __restrict__ sel,
               float* __restrict__ beams)
{
    __shared__ float Asm[8][H_];
    const int t = threadIdx.x;
    const int base = blockIdx.x * 8;
    const int s = blockIdx.x >> 1, j = blockIdx.x & 1;
    const int idx = sel[s * 2 + j];
    const int n = idx & 3;

    const float4* src = (const float4*)(projg + (size_t)base * H_);
    #pragma unroll
    for (int q = 0; q < 4; q++) {
        int i4 = t + q * 256;
        ((float4*)&Asm[0][0])[i4] = src[i4];
    }
    __syncthreads();

    const float* Wn  = Wb + (size_t)n * H_ * H_;
    const float* bbn = bb + n * H_;
    const int r = t >> 5, g = t & 31;

    #pragma unroll
    for (int cc = 0; cc < 4; cc++) {
        int c = cc * 128 + g * 4;
        float a0 = 0.f, a1 = 0.f, a2 = 0.f, a3 = 0.f;
        #pragma unroll 4
        for (int k = 0; k < H_; k++) {
            float a = Asm[r][k];
            float4 w = *(const float4*)(Wn + (size_t)k * H_ + c);
            a0 += a * w.x; a1 += a * w.y; a2 += a * w.z; a3 += a * w.w;
        }
        float4 o;
        o.x = gelu_f(a0 + bbn[c + 0]);
        o.y = gelu_f(a1 + bbn[c + 1]);
        o.z = gelu_f(a2 + bbn[c + 2]);
        o.w = gelu_f(a3 + bbn[c + 3]);
        *(float4*)(beams + ((size_t)base + r) * H_ + c) = o;
    }
}

__global__ __launch_bounds__(256)
void final_add_k(const float* __restrict__ beams, const float* __restrict__ hidden,
                 float* __restrict__ out)
{
    size_t tid = (size_t)blockIdx.x * 256 + threadIdx.x;
    const size_t total = (size_t)B_ * S_ * (H_ / 4);
    if (tid >= total) return;
    int h4 = tid & (H_ / 4 - 1);
    int s  = (tid >> 7) & (S_ - 1);
    int b  = tid >> 18;
    float4 v  = ((const float4*)(beams + ((size_t)(s * 2 + 0) * 8 + b) * H_))[h4];
    float4 hd = ((const float4*)(hidden + ((size_t)b * S_ + s) * H_))[h4];
    v.x += hd.x; v.y += hd.y; v.z += hd.z; v.w += hd.w;
    ((float4*)(out + ((size_t)b * S_ + s) * H_))[h4] = v;
}

extern "C" void kernel_launch(void* const* d_in, const int* in_sizes, int n_in,
                              void* d_out, int out_size, void* d_ws, size_t ws_size,
                              hipStream_t stream)
{
    const float* hidden = (const float*)d_in[0];
    const float* We1 = (const float*)d_in[1];
    const float* be1 = (const float*)d_in[2];
    const float* We2 = (const float*)d_in[3];
    const float* be2 = (const float*)d_in[4];
    const float* We3 = (const float*)d_in[5];
    const float* be3 = (const float*)d_in[6];
    const float* Wp  = (const float*)d_in[7];
    const float* bp  = (const float*)d_in[8];
    const float* Wb  = (const float*)d_in[9];
    const float* bb  = (const float*)d_in[10];
    (void)in_sizes; (void)n_in; (void)ws_size;

    // d_ws: beams 64MB | R1 64MB (projc 16 + thc/h2 16 + h1 32)
    float* beams = (float*)d_ws;
    float* R1    = beams + 16777216;
    float* projc = R1;                    // 8192*512
    float* thc   = R1 + 4194304;          // 8192*512 (doubles as h2)
    float* h1    = R1 + 8388608;          // 8192*1024
    float* h2    = thc;
    float* projg = R1;                    // pass 2: 32768*512

    // d_out tail (dead until final_add): weights + small buffers
    float* outf = (float*)d_out;
    float* wreg = outf + (out_size - 2359296);
    _Float16* WpP  = (_Float16*)wreg;                 // 524288 h
    _Float16* WbP  = WpP + 524288;                    // 4*524288 h
    _Float16* We1P = WbP + 2097152;                   // 1048576 h
    _Float16* We2P = We1P + 1048576;                  // 1048576 h
    float* evb = wreg - 131072;
    float* scb = evb - 16384;
    int*   sel = (int*)(scb - 4096);

    // ---- weight prep (every launch; deterministic) ----
    prep_k<<<128, 256, 0, stream>>>(Wp, WpP, 512, 512);
    for (int n = 0; n < 4; n++)
        prep_k<<<128, 256, 0, stream>>>(Wb + (size_t)n * 262144, WbP + (size_t)n * 524288, 512, 512);
    prep_k<<<256, 256, 0, stream>>>(We1, We1P, 512, 1024);
    prep_k<<<256, 256, 0, stream>>>(We2, We2P, 1024, 512);

    for (int d = 0; d < 3; d++) {
        const int K  = (d == 0) ? 1 : 2;
        const int Mp = S_ * K * B_;
        const int NC = Mp / CM_;

        // ---- pass 1: scores (chunked; states discarded) ----
        for (int c = 0; c < NC; c++) {
            dim3 gp(CM_ / 64, 4);
            if (d == 0)
                mgemm_k<false, 1><<<gp, 256, 0, stream>>>(hidden, WpP, bp, projc,
                                                          512, 512, c * CM_, nullptr);
            else
                mgemm_k<false, 0><<<gp, 256, 0, stream>>>(beams + (size_t)c * CM_ * H_,
                                                          WpP, bp, projc, 512, 512, 0, nullptr);
            for (int n = 0; n < 4; n++) {
                mgemm_k<true, 0><<<gp, 256, 0, stream>>>(projc, WbP + (size_t)n * 524288,
                                                         bb + n * H_, thc, 512, 512, 0, nullptr);
                dim3 g1(CM_ / 64, 8);
                mgemm_k<true, 0><<<g1, 256, 0, stream>>>(thc, We1P, be1, h1, 1024, 512, 0, nullptr);
                dim3 g2(CM_ / 64, 4);
                mgemm_k<true, 0><<<g2, 256, 0, stream>>>(h1, We2P, be2, h2, 512, 1024, 0, nullptr);
                score1_k<<<CM_ / 4, 256, 0, stream>>>(h2, We3, be3, evb, c * CM_, n);
            }
        }

        // ---- selection ----
        const int nsc = S_ * K * 4;
        score2_k<<<(nsc + 255) / 256, 256, 0, stream>>>(evb, scb, nsc);
        select_k<<<(S_ + 255) / 256, 256, 0, stream>>>(scb, sel, K);

        // ---- pass 2: recompute selected states ----
        dim3 gg(32768 / 64, 4);
        if (d == 0)
            mgemm_k<false, 3><<<gg, 256, 0, stream>>>(hidden, WpP, bp, projg,
                                                      512, 512, 0, sel);
        else
            mgemm_k<false, 2><<<gg, 256, 0, stream>>>(beams, WpP, bp, projg,
                                                      512, 512, 0, sel);
        branch2_k<<<S_ * 2, 256, 0, stream>>>(projg, Wb, bb, sel, beams);
    }

    final_add_k<<<(int)(((size_t)B_ * S_ * (H_ / 4) + 255) / 256), 256, 0, stream>>>(
        beams, hidden, outf);
}

// Round 5
// 5185.744 us; speedup vs baseline: 3.4807x; 1.3325x over previous
//
#include <hip/hip_runtime.h>

#define S_  2048
#define B_  8
#define H_  512
#define H2_ 1024
#define CM_ 8192   // pass-1 chunk rows

typedef _Float16 f16x8 __attribute__((ext_vector_type(8)));
typedef _Float16 f16x4 __attribute__((ext_vector_type(4)));
typedef float    f32x4 __attribute__((ext_vector_type(4)));

__device__ __forceinline__ float gelu_f(float x){
    return 0.5f * x * (1.0f + erff(x * 0.7071067811865476f));
}

// ---------------------------------------------------------------------------
// Weight prep: decompose fp32 K×N (row-major) into 2 fp16 planes in
// MFMA-fragment order: plane[( (fc*KS + ks)*64 + l )*8 + j] holds
// B[ks*32 + (l>>4)*8 + j][fc*16 + (l&15)].  plane2 = (residual * 2048).
__global__ __launch_bounds__(256)
void prep_k(const float* __restrict__ src, _Float16* __restrict__ dst,
            int K, int N)
{
    int g = blockIdx.x * 256 + threadIdx.x;        // total = K*N/8
    int KS = K >> 5;
    int l  = g & 63;
    int rem = g >> 6;
    int ks = rem % KS;
    int fc = rem / KS;
    int kbase = ks * 32 + (l >> 4) * 8;
    int col   = fc * 16 + (l & 15);
    size_t KN = (size_t)K * N;
    #pragma unroll
    for (int j = 0; j < 8; j++) {
        float x = src[(size_t)(kbase + j) * N + col];
        _Float16 h1 = (_Float16)x;
        float r = x - (float)h1;
        _Float16 h2 = (_Float16)(r * 2048.0f);
        dst[(size_t)g * 8 + j]      = h1;
        dst[KN + (size_t)g * 8 + j] = h2;
    }
}

// ---------------------------------------------------------------------------
// Split-precision fp16x2 MFMA GEMM.  C = epi(A(f32) @ B + bias).
// BM=64, BN=128, BK=32, 256 threads (4 waves, 2x2, wave tile 32x64).
// B read directly from prepped global planes (no LDS). A staged f32->f16x2
// into frag-order LDS with XOR swizzle.
// INMAP 0: A row r at A + r*K
// INMAP 1: hidden transpose: gr=r0+r: hidden + ((gr&7)*S_ + (gr>>3))*H_
// INMAP 2: gather beams: s=r>>4, j=(r>>3)&1, b=r&7, kb=sel[s*2+j]>>2
//          -> A + ((s*2+kb)*8+b)*H_
// INMAP 3: gather hidden: s=r>>4, b=r&7 -> hidden + (b*S_+s)*H_
// OUTMAP 0: plain store
// OUTMAP 1: predicated branch store: row r belongs to pair p=r>>3;
//           store only if (sel[p]&3)==nsel  (C = beams, same row indexing)
template<bool GELU, int INMAP, int OUTMAP>
__global__ __launch_bounds__(256, 2)
void mgemm_k(const float* __restrict__ A, const _Float16* __restrict__ Bp,
             const float* __restrict__ bias, float* __restrict__ C,
             int N, int K, int r0, const int* __restrict__ sel, int nsel)
{
    __shared__ __align__(16) char smem[8192];      // 2 planes * 4 fr * 64 * 16B
    const int t    = threadIdx.x;
    const int m0   = blockIdx.x * 64;
    const int n0   = blockIdx.y * 128;
    const int lane = t & 63;
    const int wave = t >> 6;
    const int wr   = wave >> 1;                    // 0..1 row half
    const int wc   = wave & 1;                     // 0..1 col half
    const int KS   = K >> 5;
    const size_t planeStride = (size_t)K * N;      // halves

    // ---- A staging assignment: q=0..1, row=(t>>3)+32q, k0=(t&7)*4 ----
    const int srow = t >> 3;
    const int sk0  = (t & 7) * 4;
    const float* aptr[2];
    int wbyte[2];
    #pragma unroll
    for (int q = 0; q < 2; q++) {
        int row = srow + 32 * q;
        int r = m0 + row;
        size_t aoff;
        if (INMAP == 1) { int gr = r0 + r; aoff = ((size_t)(gr & 7) * S_ + (gr >> 3)) * H_; }
        else if (INMAP == 2) {
            int s = r >> 4, j = (r >> 3) & 1, b = r & 7;
            int kb = sel[s * 2 + j] >> 2;
            aoff = ((size_t)(s * 2 + kb) * 8 + b) * H_;
        }
        else if (INMAP == 3) { int s = r >> 4, b = r & 7; aoff = ((size_t)b * S_ + s) * H_; }
        else aoff = (size_t)r * K;
        aptr[q] = A + aoff + sk0;
        int e = (row & 15) + 16 * (sk0 >> 3);
        int p = e ^ (((e >> 4) & 3) << 2);
        wbyte[q] = (row >> 4) * 1024 + p * 16 + (sk0 & 4) * 2;
    }

    // ---- frag read offsets ----
    const int rl    = lane ^ (((lane >> 4) & 3) << 2);
    const int rbyte = rl * 16;

    // ---- B frag pointers (global, prepped layout) ----
    const _Float16* bjp[4];
    #pragma unroll
    for (int j = 0; j < 4; j++) {
        int fcg = (n0 >> 4) + wc * 4 + j;
        bjp[j] = Bp + (size_t)fcg * KS * 512 + lane * 8;
    }

    f32x4 accM[2][4], accX[2][4];
    #pragma unroll
    for (int i = 0; i < 2; i++)
        #pragma unroll
        for (int j = 0; j < 4; j++) { accM[i][j] = (f32x4)0.0f; accX[i][j] = (f32x4)0.0f; }

    for (int ks = 0; ks < KS; ks++) {
        // global loads for this step (A f32, B frags) — issue early
        float4 av[2];
        #pragma unroll
        for (int q = 0; q < 2; q++) av[q] = *(const float4*)(aptr[q] + ks * 32);
        f16x8 b1v[4], b2v[4];
        #pragma unroll
        for (int j = 0; j < 4; j++) {
            const _Float16* bp = bjp[j] + (size_t)ks * 512;
            b1v[j] = *(const f16x8*)(bp);
            b2v[j] = *(const f16x8*)(bp + planeStride);
        }

        __syncthreads();   // previous iteration's frag reads done
        #pragma unroll
        for (int q = 0; q < 2; q++) {
            const float xs[4] = {av[q].x, av[q].y, av[q].z, av[q].w};
            f16x4 hv1, hv2;
            #pragma unroll
            for (int e = 0; e < 4; e++) {
                float x = xs[e];
                _Float16 h1 = (_Float16)x;
                hv1[e] = h1;
                hv2[e] = (_Float16)((x - (float)h1) * 2048.0f);
            }
            *(f16x4*)(smem + wbyte[q])        = hv1;
            *(f16x4*)(smem + 4096 + wbyte[q]) = hv2;
        }
        __syncthreads();

        f16x8 a1[2], a2[2];
        #pragma unroll
        for (int i = 0; i < 2; i++) {
            int off = (wr * 2 + i) * 1024 + rbyte;
            a1[i] = *(const f16x8*)(smem + off);
            a2[i] = *(const f16x8*)(smem + 4096 + off);
        }
        #pragma unroll
        for (int i = 0; i < 2; i++)
            #pragma unroll
            for (int j = 0; j < 4; j++)
                accM[i][j] = __builtin_amdgcn_mfma_f32_16x16x32_f16(a1[i], b1v[j], accM[i][j], 0, 0, 0);
        #pragma unroll
        for (int i = 0; i < 2; i++)
            #pragma unroll
            for (int j = 0; j < 4; j++)
                accX[i][j] = __builtin_amdgcn_mfma_f32_16x16x32_f16(a1[i], b2v[j], accX[i][j], 0, 0, 0);
        #pragma unroll
        for (int i = 0; i < 2; i++)
            #pragma unroll
            for (int j = 0; j < 4; j++)
                accX[i][j] = __builtin_amdgcn_mfma_f32_16x16x32_f16(a2[i], b1v[j], accX[i][j], 0, 0, 0);
    }

    // ---- epilogue ----
    const float inv2048 = 4.8828125e-4f;
    #pragma unroll
    for (int i = 0; i < 2; i++) {
        int rbase = m0 + wr * 32 + i * 16 + ((lane >> 4) << 2);
        bool ok = true;
        if (OUTMAP == 1) ok = ((sel[rbase >> 3] & 3) == nsel);
        if (!ok) continue;
        #pragma unroll
        for (int j = 0; j < 4; j++) {
            int col = n0 + wc * 64 + j * 16 + (lane & 15);
            float bv = bias[col];
            #pragma unroll
            for (int r = 0; r < 4; r++) {
                float c = accM[i][j][r] + accX[i][j][r] * inv2048 + bv;
                if (GELU) c = gelu_f(c);
                C[(size_t)(rbase + r) * N + col] = c;
            }
        }
    }
}

// ---------------------------------------------------------------------------
// One wave per row of h2: ev[(pr>>3)*32 + n*8 + (pr&7)] = sigmoid(dot + be3)
__global__ __launch_bounds__(256)
void score1_k(const float* __restrict__ h2, const float* __restrict__ We3,
              const float* __restrict__ be3, float* __restrict__ ev,
              int pr0, int n)
{
    int row  = blockIdx.x * 4 + (threadIdx.x >> 6);
    int lane = threadIdx.x & 63;
    const float* p = h2 + (size_t)row * H_;
    float s = 0.f;
    #pragma unroll
    for (int j = 0; j < H_ / 64; j++) s += p[lane + 64 * j] * We3[lane + 64 * j];
    #pragma unroll
    for (int off = 32; off > 0; off >>= 1) s += __shfl_down(s, off, 64);
    if (lane == 0) {
        int pr = pr0 + row;
        ev[(size_t)(pr >> 3) * 32 + n * 8 + (pr & 7)] = 1.0f / (1.0f + expf(-(s + be3[0])));
    }
}

__global__ __launch_bounds__(256)
void score2_k(const float* __restrict__ ev, float* __restrict__ sc, int n)
{
    int i = blockIdx.x * 256 + threadIdx.x;
    if (i >= n) return;
    float s = 0.f;
    #pragma unroll
    for (int b = 0; b < 8; b++) s += ev[i * 8 + b];
    sc[i] = (s * 0.125f) / 0.8f;
}

__global__ __launch_bounds__(256)
void select_k(const float* __restrict__ sc, int* __restrict__ sel, int K)
{
    int s = blockIdx.x * 256 + threadIdx.x;
    if (s >= S_) return;
    int K4 = K * 4;
    float cand[8];
    for (int k = 0; k < K; k++) {
        const float* scp = sc + (size_t)(s * K + k) * 4;
        bool keep[4] = {false, false, false, false};
        int count = 0;
        for (int i = 0; i < 4; i++) {
            float mind = INFINITY;
            for (int j = 0; j < 4; j++)
                if (keep[j]) mind = fminf(mind, fabsf(scp[i] - scp[j]));
            bool ki = ((count == 0) || (mind >= 0.1f)) && (count < 2);
            keep[i] = ki;
            if (ki) count++;
        }
        for (int i = 0; i < 4; i++) cand[k * 4 + i] = keep[i] ? scp[i] : -INFINITY;
    }
    int i0 = 0;
    for (int i = 1; i < K4; i++) if (cand[i] > cand[i0]) i0 = i;
    int i1 = -1;
    for (int i = 0; i < K4; i++) {
        if (i == i0) continue;
        if (i1 < 0 || cand[i] > cand[i1]) i1 = i;
    }
    if (!(cand[i1] > -INFINITY)) i1 = i0;
    sel[s * 2 + 0] = i0;
    sel[s * 2 + 1] = i1;
}

__global__ __launch_bounds__(256)
void final_add_k(const float* __restrict__ beams, const float* __restrict__ hidden,
                 float* __restrict__ out)
{
    size_t tid = (size_t)blockIdx.x * 256 + threadIdx.x;
    const size_t total = (size_t)B_ * S_ * (H_ / 4);
    if (tid >= total) return;
    int h4 = tid & (H_ / 4 - 1);
    int s  = (tid >> 7) & (S_ - 1);
    int b  = tid >> 18;
    float4 v  = ((const float4*)(beams + ((size_t)(s * 2 + 0) * 8 + b) * H_))[h4];
    float4 hd = ((const float4*)(hidden + ((size_t)b * S_ + s) * H_))[h4];
    v.x += hd.x; v.y += hd.y; v.z += hd.z; v.w += hd.w;
    ((float4*)(out + ((size_t)b * S_ + s) * H_))[h4] = v;
}

extern "C" void kernel_launch(void* const* d_in, const int* in_sizes, int n_in,
                              void* d_out, int out_size, void* d_ws, size_t ws_size,
                              hipStream_t stream)
{
    const float* hidden = (const float*)d_in[0];
    const float* We1 = (const float*)d_in[1];
    const float* be1 = (const float*)d_in[2];
    const float* We2 = (const float*)d_in[3];
    const float* be2 = (const float*)d_in[4];
    const float* We3 = (const float*)d_in[5];
    const float* be3 = (const float*)d_in[6];
    const float* Wp  = (const float*)d_in[7];
    const float* bp  = (const float*)d_in[8];
    const float* Wb  = (const float*)d_in[9];
    const float* bb  = (const float*)d_in[10];
    (void)in_sizes; (void)n_in; (void)ws_size;

    // d_ws: beams 64MB | R1 64MB (projc 16 + thc/h2 16 + h1 32; projg = all of R1)
    float* beams = (float*)d_ws;
    float* R1    = beams + 16777216;
    float* projc = R1;                    // 8192*512
    float* thc   = R1 + 4194304;          // 8192*512 (doubles as h2)
    float* h1    = R1 + 8388608;          // 8192*1024
    float* h2    = thc;
    float* projg = R1;                    // pass 2: 32768*512

    // d_out tail (dead until final_add): weights + small buffers
    float* outf = (float*)d_out;
    float* wreg = outf + (out_size - 2359296);
    _Float16* WpP  = (_Float16*)wreg;                 // 524288 h
    _Float16* WbP  = WpP + 524288;                    // 4*524288 h
    _Float16* We1P = WbP + 2097152;                   // 1048576 h
    _Float16* We2P = We1P + 1048576;                  // 1048576 h
    float* evb = wreg - 131072;
    float* scb = evb - 16384;
    int*   sel = (int*)(scb - 4096);

    // ---- weight prep (every launch; deterministic) ----
    prep_k<<<128, 256, 0, stream>>>(Wp, WpP, 512, 512);
    for (int n = 0; n < 4; n++)
        prep_k<<<128, 256, 0, stream>>>(Wb + (size_t)n * 262144, WbP + (size_t)n * 524288, 512, 512);
    prep_k<<<256, 256, 0, stream>>>(We1, We1P, 512, 1024);
    prep_k<<<256, 256, 0, stream>>>(We2, We2P, 1024, 512);

    for (int d = 0; d < 3; d++) {
        const int K  = (d == 0) ? 1 : 2;
        const int Mp = S_ * K * B_;
        const int NC = Mp / CM_;

        // ---- pass 1: scores (chunked; states discarded) ----
        for (int c = 0; c < NC; c++) {
            dim3 gp(CM_ / 64, 4);
            if (d == 0)
                mgemm_k<false, 1, 0><<<gp, 256, 0, stream>>>(hidden, WpP, bp, projc,
                                                             512, 512, c * CM_, nullptr, 0);
            else
                mgemm_k<false, 0, 0><<<gp, 256, 0, stream>>>(beams + (size_t)c * CM_ * H_,
                                                             WpP, bp, projc, 512, 512, 0, nullptr, 0);
            for (int n = 0; n < 4; n++) {
                mgemm_k<true, 0, 0><<<gp, 256, 0, stream>>>(projc, WbP + (size_t)n * 524288,
                                                            bb + n * H_, thc, 512, 512, 0, nullptr, 0);
                dim3 g1(CM_ / 64, 8);
                mgemm_k<true, 0, 0><<<g1, 256, 0, stream>>>(thc, We1P, be1, h1, 1024, 512, 0, nullptr, 0);
                dim3 g2(CM_ / 64, 4);
                mgemm_k<true, 0, 0><<<g2, 256, 0, stream>>>(h1, We2P, be2, h2, 512, 1024, 0, nullptr, 0);
                score1_k<<<CM_ / 4, 256, 0, stream>>>(h2, We3, be3, evb, c * CM_, n);
            }
        }

        // ---- selection ----
        const int nsc = S_ * K * 4;
        score2_k<<<(nsc + 255) / 256, 256, 0, stream>>>(evb, scb, nsc);
        select_k<<<(S_ + 255) / 256, 256, 0, stream>>>(scb, sel, K);

        // ---- pass 2: recompute selected states (4 predicated branch GEMMs) ----
        dim3 gg(32768 / 64, 4);
        if (d == 0)
            mgemm_k<false, 3, 0><<<gg, 256, 0, stream>>>(hidden, WpP, bp, projg,
                                                         512, 512, 0, sel, 0);
        else
            mgemm_k<false, 2, 0><<<gg, 256, 0, stream>>>(beams, WpP, bp, projg,
                                                         512, 512, 0, sel, 0);
        for (int n = 0; n < 4; n++)
            mgemm_k<true, 0, 1><<<gg, 256, 0, stream>>>(projg, WbP + (size_t)n * 524288,
                                                        bb + n * H_, beams, 512, 512, 0, sel, n);
    }

    final_add_k<<<(int)(((size_t)B_ * S_ * (H_ / 4) + 255) / 256), 256, 0, stream>>>(
        beams, hidden, outf);
}